// Round 12
// baseline (136.884 us; speedup 1.0000x reference)
//
#include <hip/hip_runtime.h>
#include <hip/hip_fp16.h>

#define N_NODES 100000
#define E_EDGES 1600000
#define IN_C 128
#define HID_C 64
#define OUT_C 32
#define BNODES 64                                   // nodes per bucket (dst>>6)
#define NBUCK ((N_NODES + BNODES - 1) / BNODES)     // 1563
#define MAXB 2048                                   // bucket cap (mean 1024, sigma~32)
#define NCHUNK 256                                  // edge chunks (privatized hist)
#define CHUNK_E (E_EDGES / NCHUNK)                  // 6250

typedef __attribute__((ext_vector_type(8))) short short8;   // 8 bf16 (4 VGPRs)
typedef __attribute__((ext_vector_type(4))) float f32x4;    // MFMA accumulator

__device__ __forceinline__ unsigned short f2bf(float f) {   // rn-to-nearest-even bf16
    union { float f; unsigned u; } v; v.f = f;
    return (unsigned short)((v.u + 0x7fffu + ((v.u >> 16) & 1u)) >> 16);
}
__device__ __forceinline__ float bf2f(unsigned short b) {
    union { unsigned u; float f; } v; v.u = ((unsigned)b) << 16;
    return v.f;
}

// chunk<->block swizzle: consecutive chunks land on the same XCD (blockIdx%8 heuristic).
__device__ __forceinline__ int chunk_of_block(int b) { return (b & 7) * (NCHUNK / 8) + (b >> 3); }

// ---- init: zero bucket cursors + pre-split W1 into TRANSPOSED bf16 hi/lo tables
//      Wt[c][k] (contiguous 16B per 8-k fragment; 16 KB each -> L1-resident in gemm1).
//      Folded into one dispatch (grid 32 covers both jobs). ----
__global__ void init_kernel(int* __restrict__ gcur, const float* __restrict__ W1,
                            unsigned short* __restrict__ WtH, unsigned short* __restrict__ WtL) {
    int i = blockIdx.x * 256 + threadIdx.x;
    if (i < 1568) gcur[i] = 0;
    if (i < IN_C * HID_C) {                        // W1[k][c] row-major -> Wt[c][k]
        int k = i >> 6, c = i & 63;
        float w = W1[i];
        unsigned short h = f2bf(w);
        WtH[c * IN_C + k] = h;
        WtL[c * IN_C + k] = f2bf(w - bf2f(h));
    }
}

// ---- single-pass bucketing: per-chunk LDS histogram -> atomic window reservation in
//      gcur -> scatter into PADDED per-bucket regions (b*MAXB). (Round-9 lesson:
//      direct per-node scatter = 134 us of random-line RMW; dense windows = ~9 us.) ----
__global__ __launch_bounds__(1024) void bucket_scatter_kernel(const int* __restrict__ src,
                                                              const int* __restrict__ dst,
                                                              int* __restrict__ gcur,
                                                              unsigned* __restrict__ pairs) {
    __shared__ int h[NBUCK];                        // count -> base cursor (reused)
    for (int i = threadIdx.x; i < NBUCK; i += 1024) h[i] = 0;
    __syncthreads();
    const int chunk = chunk_of_block(blockIdx.x);
    const int base = chunk * CHUNK_E;
    int dc[7];                                      // ceil(6250/1024) = 7
    int nj = 0;
    for (int j = threadIdx.x; j < CHUNK_E; j += 1024) {
        int d = dst[base + j];
        dc[nj++] = d;
        atomicAdd(&h[d >> 6], 1);
    }
    __syncthreads();
    for (int i = threadIdx.x; i < NBUCK; i += 1024) {
        int c = h[i];
        if (c > 0) h[i] = atomicAdd(&gcur[i], c);   // reserve window; h becomes cursor
    }
    __syncthreads();
    nj = 0;
    for (int j = threadIdx.x; j < CHUNK_E; j += 1024) {
        int d = dc[nj++];
        int pos = atomicAdd(&h[d >> 6], 1);
        pairs[(unsigned)(d >> 6) * MAXB + (unsigned)pos] =
            ((unsigned)src[base + j] << 6) | (unsigned)(d & 63);
    }
}

// ---- per-bucket counting sort -> node-level padded CSR, in place (LDS stage). ----
__global__ __launch_bounds__(256) void bucket_sort_kernel(const int* __restrict__ gcur,
                                                          unsigned* __restrict__ pairs,
                                                          int* __restrict__ row_beg,
                                                          int* __restrict__ row_end,
                                                          float* __restrict__ dinv) {
    __shared__ unsigned sp[MAXB];
    __shared__ int hcnt[BNODES], scn[BNODES], cur[BNODES];
    const int b = blockIdx.x;
    const int beg = b * MAXB;
    int cnt = gcur[b];
    if (cnt > MAXB) cnt = MAXB;                     // safety clamp (cap is 32 sigma)
    if (threadIdx.x < BNODES) hcnt[threadIdx.x] = 0;
    __syncthreads();
    for (int j = threadIdx.x; j < cnt; j += 256) {
        unsigned p = pairs[beg + j];
        sp[j] = p;
        atomicAdd(&hcnt[p & 63], 1);
    }
    __syncthreads();
    if (threadIdx.x < BNODES) scn[threadIdx.x] = hcnt[threadIdx.x];
    __syncthreads();
    for (int off = 1; off < BNODES; off <<= 1) {
        int t = 0;
        if (threadIdx.x < BNODES && threadIdx.x >= off) t = scn[threadIdx.x - off];
        __syncthreads();
        if (threadIdx.x < BNODES) scn[threadIdx.x] += t;
        __syncthreads();
    }
    if (threadIdx.x < BNODES) {
        int ex = scn[threadIdx.x] - hcnt[threadIdx.x];   // exclusive
        cur[threadIdx.x] = ex;
        int node = b * BNODES + threadIdx.x;
        if (node < N_NODES) {
            row_beg[node] = beg + ex;
            row_end[node] = beg + ex + hcnt[threadIdx.x];
            dinv[node] = rsqrtf((float)hcnt[threadIdx.x] + 1.0f);
        }
    }
    __syncthreads();
    for (int j = threadIdx.x; j < cnt; j += 256) {
        unsigned p = sp[j];
        int pos = atomicAdd(&cur[p & 63], 1);
        pairs[beg + pos] = p >> 6;                      // now plain src index
    }
}

// ---- hs(fp16) = dinv[row] * (x @ W1) on the MATRIX cores (bf16 hi/lo split:
//      x@W ~= xh*Wh + xl*Wh + xh*Wl, fp32 accum -> added error ~1e-5, far below the
//      fp16 storage ulp). 64 rows/block, 4 waves x (16 rows x 64 cols); x staged in
//      LDS per 32-k step via round-11's proven full-line pattern; W fragments from
//      L1-resident global Wt tables (16B contiguous per fragment).
//      Layouts (gfx950, verified family): A row=lane&15, k=(lane>>4)*8+j;
//      B col=lane&15, same k; D col=lane&15, row=(lane>>4)*4+reg. ----
__global__ __launch_bounds__(256) void gemm1_kernel(const float* __restrict__ x,
                                                    const unsigned short* __restrict__ WtH,
                                                    const unsigned short* __restrict__ WtL,
                                                    const float* __restrict__ dinv,
                                                    __half* __restrict__ hs) {
    __shared__ float xt[64 * 36];                  // 9.2 KB x tile, row stride 36 (pad)
    const int l = threadIdx.x & 63;                // lane
    const int wv = threadIdx.x >> 6;               // wave 0..3 -> rows wv*16..wv*16+15
    const int row0 = blockIdx.x * 64;
    const int rA = l & 15;                         // A row / B col / D col within tile
    const int kg = l >> 4;                         // k-group 0..3
    const float4* x4 = (const float4*)x;

    f32x4 acc[4];
#pragma unroll
    for (int n = 0; n < 4; ++n) acc[n] = (f32x4){0.f, 0.f, 0.f, 0.f};

    for (int ks = 0; ks < 4; ++ks) {               // K-steps of 32
        __syncthreads();
        // stage x: 64 rows x 8 float4; per instr 8 rows x 128 B contiguous (full lines)
#pragma unroll
        for (int i = 0; i < 2; ++i) {
            int g = i * 256 + threadIdx.x;
            int r = g >> 3, k4 = g & 7;
            int rg = min(row0 + r, N_NODES - 1);
            float4 v = x4[(size_t)rg * (IN_C / 4) + ks * 8 + k4];
            *(float4*)(xt + r * 36 + k4 * 4) = v;
        }
        __syncthreads();
        // A fragment: 8 consecutive fp32 -> split into bf16 hi/lo
        const float* xp = xt + (wv * 16 + rA) * 36 + kg * 8;
        float4 xa = *(const float4*)xp;
        float4 xb = *(const float4*)(xp + 4);
        float xs[8] = {xa.x, xa.y, xa.z, xa.w, xb.x, xb.y, xb.z, xb.w};
        short8 ah, al;
#pragma unroll
        for (int b = 0; b < 8; ++b) {
            unsigned short hbits = f2bf(xs[b]);
            ah[b] = (short)hbits;
            al[b] = (short)f2bf(xs[b] - bf2f(hbits));
        }
        const int kb = ks * 32 + kg * 8;
#pragma unroll
        for (int n = 0; n < 4; ++n) {
            int c = n * 16 + rA;
            short8 bh = *(const short8*)(WtH + c * IN_C + kb);
            short8 bl = *(const short8*)(WtL + c * IN_C + kb);
            acc[n] = __builtin_amdgcn_mfma_f32_16x16x32_bf16(ah, bh, acc[n], 0, 0, 0);
            acc[n] = __builtin_amdgcn_mfma_f32_16x16x32_bf16(al, bh, acc[n], 0, 0, 0);
            acc[n] = __builtin_amdgcn_mfma_f32_16x16x32_bf16(ah, bl, acc[n], 0, 0, 0);
        }
    }
    // epilogue: D col=rA, row=kg*4+j; scale by dinv, fp16 store (L2 merges the
    // 16-lane x 2B runs of the same rows into full lines)
#pragma unroll
    for (int j = 0; j < 4; ++j) {
        int row = row0 + wv * 16 + kg * 4 + j;
        if (row < N_NODES) {
            float dv = dinv[row];
#pragma unroll
            for (int n = 0; n < 4; ++n)
                hs[(size_t)row * HID_C + n * 16 + rA] = __float2half(acc[n][j] * dv);
        }
    }
}

// ---- layer-1 aggregate + FUSED gemm2 (round-4/7 proven form, 42.2 us): 16 lanes x
//      float2 per node (4 nodes/wave), full 128 B rows; col coalesced by 8 lanes +
//      __shfl broadcast + next-chunk prefetch. Epilogue: h2 row staged in 2 KB LDS
//      tile; gemm2 vs 8 KB LDS W2 copy, k ascending -> bit-identical gs.
//      gs must NOT alias hs. ----
__global__ __launch_bounds__(256) void agg1_kernel(const int* __restrict__ row_beg,
                                                   const int* __restrict__ row_end,
                                                   const int* __restrict__ col,
                                                   const float2* __restrict__ hsf,
                                                   const float* __restrict__ dinv,
                                                   const float* __restrict__ b1,
                                                   const float* __restrict__ W2,
                                                   __half* __restrict__ gs) {
    __shared__ float sW[HID_C * OUT_C];            // 8 KB W2 copy
    __shared__ __half2 sh2[16][HID_C / 2];         // 2 KB h2 tile (16 nodes x 64 ch)
    for (int i = threadIdx.x; i < HID_C * OUT_C; i += 256) sW[i] = W2[i];

    const int nl = threadIdx.x >> 4;               // node slot in block (0..15)
    const int node = blockIdx.x * 16 + nl;         // grid 6250 * 16 = exactly N
    const int lane = threadIdx.x & 15;             // float2 index: channels 4*lane..4*lane+3
    const int beg = row_beg[node], end = row_end[node];
    float2 u = hsf[(size_t)node * 16 + lane];      // self loop
    __half2* uh = (__half2*)&u;
    float2 t0 = __half22float2(uh[0]), t1 = __half22float2(uh[1]);
    float a0 = t0.x, a1 = t0.y, a2 = t1.x, a3 = t1.y;

    int j = beg;
    int idx0 = j + (lane & 7);
    int cv = (idx0 < end) ? col[idx0] : 0;         // current chunk's indices (coalesced)
    while (j + 8 <= end) {
        int jn = j + 8;
        int idxn = jn + (lane & 7);
        int cvn = (idxn < end) ? col[idxn] : 0;    // prefetch next chunk
        int s[8];
#pragma unroll
        for (int e = 0; e < 8; ++e) s[e] = __shfl(cv, e, 8);
        float2 v[8];
#pragma unroll
        for (int e = 0; e < 8; ++e) v[e] = hsf[(size_t)s[e] * 16 + lane];
        cv = cvn;
#pragma unroll
        for (int e = 0; e < 8; ++e) {
            __half2* vh = (__half2*)&v[e];
            float2 w0 = __half22float2(vh[0]), w1 = __half22float2(vh[1]);
            a0 += w0.x; a1 += w0.y; a2 += w1.x; a3 += w1.y;
        }
        j = jn;
    }
    const int tail = end - j;                      // 0..7, cv already holds tail indices
    for (int e = 0; e < tail; ++e) {
        int s = __shfl(cv, e, 8);
        float2 v = hsf[(size_t)s * 16 + lane];
        __half2* vh = (__half2*)&v;
        float2 w0 = __half22float2(vh[0]), w1 = __half22float2(vh[1]);
        a0 += w0.x; a1 += w0.y; a2 += w1.x; a3 += w1.y;
    }
    const float dv = dinv[node];
    float4 bb = ((const float4*)b1)[lane];
    __half2 p0 = __floats2half2_rn(fmaxf(dv * a0 + bb.x, 0.f), fmaxf(dv * a1 + bb.y, 0.f));
    __half2 p1 = __floats2half2_rn(fmaxf(dv * a2 + bb.z, 0.f), fmaxf(dv * a3 + bb.w, 0.f));
    sh2[nl][lane * 2] = p0;
    sh2[nl][lane * 2 + 1] = p1;
    __syncthreads();                               // covers sW and sh2

    // gemm2 phase: thread -> (node nl, out channels oc, oc+1); k order 0..63 sequential
    const int oc = lane * 2;
    float o0 = 0.f, o1 = 0.f;
#pragma unroll
    for (int k2 = 0; k2 < HID_C / 2; ++k2) {
        float2 hv = __half22float2(sh2[nl][k2]);
        const float* w0 = sW + (2 * k2) * OUT_C + oc;
        const float* w1 = sW + (2 * k2 + 1) * OUT_C + oc;
        o0 = fmaf(hv.x, w0[0], o0); o1 = fmaf(hv.x, w0[1], o1);
        o0 = fmaf(hv.y, w1[0], o0); o1 = fmaf(hv.y, w1[1], o1);
    }
    *(__half2*)(gs + (size_t)node * OUT_C + oc) = __floats2half2_rn(o0 * dv, o1 * dv);
}

// ---- layer-2 aggregate: 8 lanes x float2 per node (8 nodes/wave), full 64 B rows,
//      same coalesced-col + shfl + prefetch structure. ----
__global__ void agg2_kernel(const int* __restrict__ row_beg, const int* __restrict__ row_end,
                            const int* __restrict__ col,
                            const float2* __restrict__ gsf, const float* __restrict__ dinv,
                            const float* __restrict__ b2, float* __restrict__ out) {
    const int node = blockIdx.x * 32 + (threadIdx.x >> 3);
    const int lane = threadIdx.x & 7;              // float2 index: channels 4*lane..4*lane+3
    if (node >= N_NODES) return;
    const int beg = row_beg[node], end = row_end[node];
    float2 u = gsf[(size_t)node * 8 + lane];       // self loop
    __half2* uh = (__half2*)&u;
    float2 t0 = __half22float2(uh[0]), t1 = __half22float2(uh[1]);
    float a0 = t0.x, a1 = t0.y, a2 = t1.x, a3 = t1.y;

    int j = beg;
    int idx0 = j + lane;
    int cv = (idx0 < end) ? col[idx0] : 0;
    while (j + 8 <= end) {
        int jn = j + 8;
        int idxn = jn + lane;
        int cvn = (idxn < end) ? col[idxn] : 0;    // prefetch next chunk
        int s[8];
#pragma unroll
        for (int e = 0; e < 8; ++e) s[e] = __shfl(cv, e, 8);
        float2 v[8];
#pragma unroll
        for (int e = 0; e < 8; ++e) v[e] = gsf[(size_t)s[e] * 8 + lane];
        cv = cvn;
#pragma unroll
        for (int e = 0; e < 8; ++e) {
            __half2* vh = (__half2*)&v[e];
            float2 w0 = __half22float2(vh[0]), w1 = __half22float2(vh[1]);
            a0 += w0.x; a1 += w0.y; a2 += w1.x; a3 += w1.y;
        }
        j = jn;
    }
    const int tail = end - j;
    for (int e = 0; e < tail; ++e) {
        int s = __shfl(cv, e, 8);
        float2 v = gsf[(size_t)s * 8 + lane];
        __half2* vh = (__half2*)&v;
        float2 w0 = __half22float2(vh[0]), w1 = __half22float2(vh[1]);
        a0 += w0.x; a1 += w0.y; a2 += w1.x; a3 += w1.y;
    }
    float dv = dinv[node];
    float4 bb = ((const float4*)b2)[lane];
    float4 o;
    o.x = dv * a0 + bb.x;
    o.y = dv * a1 + bb.y;
    o.z = dv * a2 + bb.z;
    o.w = dv * a3 + bb.w;
    *(float4*)(out + (size_t)node * OUT_C + lane * 4) = o;
}

extern "C" void kernel_launch(void* const* d_in, const int* in_sizes, int n_in,
                              void* d_out, int out_size, void* d_ws, size_t ws_size,
                              hipStream_t stream) {
    const float* x  = (const float*)d_in[0];   // [N,128]
    const int*   ei = (const int*)d_in[1];     // [2,E]
    const float* W1 = (const float*)d_in[2];   // [128,64]
    const float* b1 = (const float*)d_in[3];   // [64]
    const float* W2 = (const float*)d_in[4];   // [64,32]
    const float* b2 = (const float*)d_in[5];   // [32]
    float* out = (float*)d_out;                // [N,32]

    const int* srcv = ei;
    const int* dstv = ei + E_EDGES;

    // workspace layout (~33 MB; ws is ~268 MB). gs is a DEDICATED region (agg1 reads
    // hs while writing gs -> must not alias).
    float* dinv  = (float*)d_ws;                            // N floats
    __half* hs   = (__half*)(dinv + N_NODES);               // N*64 halves
    __half* gs   = hs + (size_t)N_NODES * HID_C;            // N*32 halves
    int* row_beg = (int*)(gs + (size_t)N_NODES * OUT_C);    // N
    int* row_end = row_beg + N_NODES;                       // N
    int* gcur    = row_end + N_NODES;                       // NBUCK (pad to 1568)
    unsigned short* WtH = (unsigned short*)(gcur + 1568);   // 8192 bf16 (hi)
    unsigned short* WtL = WtH + IN_C * HID_C;               // 8192 bf16 (lo)
    unsigned* pairs = (unsigned*)(WtL + IN_C * HID_C);      // NBUCK*MAXB (padded buckets)
    int* col = (int*)pairs;

    // init (gcur zero + W1 bf16 hi/lo split) + CSR build
    init_kernel<<<32, 256, 0, stream>>>(gcur, W1, WtH, WtL);
    bucket_scatter_kernel<<<NCHUNK, 1024, 0, stream>>>(srcv, dstv, gcur, pairs);
    bucket_sort_kernel<<<NBUCK, 256, 0, stream>>>(gcur, pairs, row_beg, row_end, dinv);

    // layer 1 GEMM on matrix cores (64 rows/block, grid 1563)
    gemm1_kernel<<<(N_NODES + 63) / 64, 256, 0, stream>>>(x, WtH, WtL, dinv, hs);

    // layer-1 aggregate + fused layer-2 GEMM
    agg1_kernel<<<N_NODES / 16, 256, 0, stream>>>(row_beg, row_end, col,
                                                  (const float2*)hs, dinv, b1, W2, gs);

    // layer-2 aggregate
    agg2_kernel<<<(N_NODES + 31) / 32, 256, 0, stream>>>(row_beg, row_end, col,
                                                         (const float2*)gs, dinv, b2, out);
}

// Round 13
// 125.660 us; speedup vs baseline: 1.0893x; 1.0893x over previous
//
#include <hip/hip_runtime.h>
#include <hip/hip_fp16.h>

#define N_NODES 100000
#define E_EDGES 1600000
#define IN_C 128
#define HID_C 64
#define OUT_C 32
#define BNODES 64                                   // nodes per bucket (dst>>6)
#define NBUCK ((N_NODES + BNODES - 1) / BNODES)     // 1563
#define MAXB 2048                                   // bucket cap (mean 1024, sigma~32)
#define NCHUNK 256                                  // edge chunks (privatized hist)
#define CHUNK_E (E_EDGES / NCHUNK)                  // 6250

// chunk<->block swizzle: consecutive chunks land on the same XCD (blockIdx%8 heuristic),
// so adjacent bucket windows (shared 64B lines) merge in one L2 instead of ping-ponging.
__device__ __forceinline__ int chunk_of_block(int b) { return (b & 7) * (NCHUNK / 8) + (b >> 3); }

// ---- zero the global bucket cursors (workspace is poisoned between iterations) ----
__global__ void zero_gcur_kernel(int* __restrict__ gcur) {
    int i = blockIdx.x * 256 + threadIdx.x;
    if (i < NBUCK) gcur[i] = 0;
}

// ---- single-pass bucketing: per-chunk LDS histogram -> atomic window reservation in
//      gcur -> scatter into PADDED per-bucket regions (b*MAXB). (Round-9 lesson:
//      direct per-node scatter = 134 us of random-line RMW; dense bucket windows
//      are what keep this at ~9 us.) ----
__global__ __launch_bounds__(1024) void bucket_scatter_kernel(const int* __restrict__ src,
                                                              const int* __restrict__ dst,
                                                              int* __restrict__ gcur,
                                                              unsigned* __restrict__ pairs) {
    __shared__ int h[NBUCK];                        // count -> base cursor (reused)
    for (int i = threadIdx.x; i < NBUCK; i += 1024) h[i] = 0;
    __syncthreads();
    const int chunk = chunk_of_block(blockIdx.x);
    const int base = chunk * CHUNK_E;
    int dc[7];                                      // ceil(6250/1024) = 7
    int nj = 0;
    for (int j = threadIdx.x; j < CHUNK_E; j += 1024) {
        int d = dst[base + j];
        dc[nj++] = d;
        atomicAdd(&h[d >> 6], 1);
    }
    __syncthreads();
    for (int i = threadIdx.x; i < NBUCK; i += 1024) {
        int c = h[i];
        if (c > 0) h[i] = atomicAdd(&gcur[i], c);   // reserve window; h becomes cursor
    }
    __syncthreads();
    nj = 0;
    for (int j = threadIdx.x; j < CHUNK_E; j += 1024) {
        int d = dc[nj++];
        int pos = atomicAdd(&h[d >> 6], 1);
        pairs[(unsigned)(d >> 6) * MAXB + (unsigned)pos] =
            ((unsigned)src[base + j] << 6) | (unsigned)(d & 63);
    }
}

// ---- per-bucket counting sort -> node-level padded CSR, in place (LDS stage). ----
__global__ __launch_bounds__(256) void bucket_sort_kernel(const int* __restrict__ gcur,
                                                          unsigned* __restrict__ pairs,
                                                          int* __restrict__ row_beg,
                                                          int* __restrict__ row_end,
                                                          float* __restrict__ dinv) {
    __shared__ unsigned sp[MAXB];
    __shared__ int hcnt[BNODES], scn[BNODES], cur[BNODES];
    const int b = blockIdx.x;
    const int beg = b * MAXB;
    int cnt = gcur[b];
    if (cnt > MAXB) cnt = MAXB;                     // safety clamp (cap is 32 sigma)
    if (threadIdx.x < BNODES) hcnt[threadIdx.x] = 0;
    __syncthreads();
    for (int j = threadIdx.x; j < cnt; j += 256) {
        unsigned p = pairs[beg + j];
        sp[j] = p;
        atomicAdd(&hcnt[p & 63], 1);
    }
    __syncthreads();
    if (threadIdx.x < BNODES) scn[threadIdx.x] = hcnt[threadIdx.x];
    __syncthreads();
    for (int off = 1; off < BNODES; off <<= 1) {
        int t = 0;
        if (threadIdx.x < BNODES && threadIdx.x >= off) t = scn[threadIdx.x - off];
        __syncthreads();
        if (threadIdx.x < BNODES) scn[threadIdx.x] += t;
        __syncthreads();
    }
    if (threadIdx.x < BNODES) {
        int ex = scn[threadIdx.x] - hcnt[threadIdx.x];   // exclusive
        cur[threadIdx.x] = ex;
        int node = b * BNODES + threadIdx.x;
        if (node < N_NODES) {
            row_beg[node] = beg + ex;
            row_end[node] = beg + ex + hcnt[threadIdx.x];
            dinv[node] = rsqrtf((float)hcnt[threadIdx.x] + 1.0f);
        }
    }
    __syncthreads();
    for (int j = threadIdx.x; j < cnt; j += 256) {
        unsigned p = sp[j];
        int pos = atomicAdd(&cur[p & 63], 1);
        pairs[beg + pos] = p >> 6;                      // now plain src index
    }
}

// ---- hs(fp16) = dinv[row] * (x @ W1), LDS-STAGED both operands per 32-k chunk,
//      64 rows/block (grid 1563 -> 6.1 blocks/CU; round-11's 128-row version was
//      GRID-limited to 3.05 blocks/CU and its stage->barrier->compute phases could
//      not overlap). xt[64][36] (pad 36 -> b128-aligned, 2-way banks = free) filled
//      with full-line coalesced loads (round-10 lesson: per-instruction line
//      coverage is what the fabric charges); sWc[32][64] staged per chunk.
//      LDS 17.2 KB. k ascending 0..127 -> bit-identical hs. ----
__global__ __launch_bounds__(256) void gemm1_kernel(const float* __restrict__ x,
                                                    const float* __restrict__ W1,
                                                    const float* __restrict__ dinv,
                                                    __half* __restrict__ hs) {
    __shared__ float xt[64 * 36];                  // 9.2 KB x tile, row stride 36 words
    __shared__ float sWc[32 * 64];                 // 8 KB W1 k-chunk
    const int row0 = blockIdx.x * 64;
    const int colg = (threadIdx.x & 7) * 8;        // 8 cols per thread
    const int rowg = (threadIdx.x >> 3) * 2;       // 2 rows per thread (32 row-groups)
    float acc[2][8];
#pragma unroll
    for (int r = 0; r < 2; ++r)
#pragma unroll
        for (int c = 0; c < 8; ++c) acc[r][c] = 0.f;

    const float4* x4 = (const float4*)x;
    const float4* w4 = (const float4*)W1;

    for (int c = 0; c < 4; ++c) {                  // k chunks of 32
        __syncthreads();                           // previous chunk's compute done
        // stage x chunk: 64 rows x 8 float4; per instr: 32 rows x 128 B contiguous
#pragma unroll
        for (int i = 0; i < 2; ++i) {
            int g = i * 256 + threadIdx.x;
            int r = g >> 3, k4 = g & 7;
            int rg = min(row0 + r, N_NODES - 1);
            float4 v = x4[(size_t)rg * (IN_C / 4) + c * 8 + k4];
            *(float4*)(xt + r * 36 + k4 * 4) = v;
        }
        // stage W chunk: rows c*32..c*32+31, all 64 cols; fully coalesced
#pragma unroll
        for (int i = 0; i < 2; ++i) {
            int f = i * 256 + threadIdx.x;         // float4 index in [0,512)
            int wr = f >> 4, wc4 = f & 15;
            *(float4*)(sWc + wr * 64 + wc4 * 4) = w4[(size_t)(c * 32 + wr) * 16 + wc4];
        }
        __syncthreads();
        // compute 32 k, ascending
#pragma unroll
        for (int k4 = 0; k4 < 8; ++k4) {
            float4 xr[2];
#pragma unroll
            for (int ri = 0; ri < 2; ++ri)
                xr[ri] = *(const float4*)(xt + (rowg + ri) * 36 + k4 * 4);
#pragma unroll
            for (int j = 0; j < 4; ++j) {
                const float4* wp = (const float4*)(sWc + (k4 * 4 + j) * 64 + colg);
                float4 w0 = wp[0], w1 = wp[1];
                float wv[8] = {w0.x, w0.y, w0.z, w0.w, w1.x, w1.y, w1.z, w1.w};
#pragma unroll
                for (int ri = 0; ri < 2; ++ri) {
                    const float* xf = (const float*)&xr[ri];
                    float xs = xf[j];
#pragma unroll
                    for (int cc = 0; cc < 8; ++cc)
                        acc[ri][cc] = fmaf(xs, wv[cc], acc[ri][cc]);
                }
            }
        }
    }
#pragma unroll
    for (int ri = 0; ri < 2; ++ri) {
        int row = row0 + rowg + ri;
        if (row < N_NODES) {
            float dv = dinv[row];
            union { float4 f; __half2 h[4]; } u;
#pragma unroll
            for (int q = 0; q < 4; ++q)
                u.h[q] = __floats2half2_rn(acc[ri][2 * q] * dv, acc[ri][2 * q + 1] * dv);
            *(float4*)(hs + (size_t)row * HID_C + colg) = u.f;   // 16 B packed store
        }
    }
}

// ---- layer-1 aggregate + FUSED gemm2 (round-4/7 proven form, 42.2 us): 16 lanes x
//      float2 per node (4 nodes/wave), full 128 B rows; col coalesced by 8 lanes +
//      __shfl broadcast + next-chunk prefetch. Epilogue: h2 row staged in 2 KB LDS
//      tile; gemm2 vs 8 KB LDS W2 copy, k ascending -> bit-identical gs.
//      gs must NOT alias hs. ----
__global__ __launch_bounds__(256) void agg1_kernel(const int* __restrict__ row_beg,
                                                   const int* __restrict__ row_end,
                                                   const int* __restrict__ col,
                                                   const float2* __restrict__ hsf,
                                                   const float* __restrict__ dinv,
                                                   const float* __restrict__ b1,
                                                   const float* __restrict__ W2,
                                                   __half* __restrict__ gs) {
    __shared__ float sW[HID_C * OUT_C];            // 8 KB W2 copy
    __shared__ __half2 sh2[16][HID_C / 2];         // 2 KB h2 tile (16 nodes x 64 ch)
    for (int i = threadIdx.x; i < HID_C * OUT_C; i += 256) sW[i] = W2[i];

    const int nl = threadIdx.x >> 4;               // node slot in block (0..15)
    const int node = blockIdx.x * 16 + nl;         // grid 6250 * 16 = exactly N
    const int lane = threadIdx.x & 15;             // float2 index: channels 4*lane..4*lane+3
    const int beg = row_beg[node], end = row_end[node];
    float2 u = hsf[(size_t)node * 16 + lane];      // self loop
    __half2* uh = (__half2*)&u;
    float2 t0 = __half22float2(uh[0]), t1 = __half22float2(uh[1]);
    float a0 = t0.x, a1 = t0.y, a2 = t1.x, a3 = t1.y;

    int j = beg;
    int idx0 = j + (lane & 7);
    int cv = (idx0 < end) ? col[idx0] : 0;         // current chunk's indices (coalesced)
    while (j + 8 <= end) {
        int jn = j + 8;
        int idxn = jn + (lane & 7);
        int cvn = (idxn < end) ? col[idxn] : 0;    // prefetch next chunk
        int s[8];
#pragma unroll
        for (int e = 0; e < 8; ++e) s[e] = __shfl(cv, e, 8);
        float2 v[8];
#pragma unroll
        for (int e = 0; e < 8; ++e) v[e] = hsf[(size_t)s[e] * 16 + lane];
        cv = cvn;
#pragma unroll
        for (int e = 0; e < 8; ++e) {
            __half2* vh = (__half2*)&v[e];
            float2 w0 = __half22float2(vh[0]), w1 = __half22float2(vh[1]);
            a0 += w0.x; a1 += w0.y; a2 += w1.x; a3 += w1.y;
        }
        j = jn;
    }
    const int tail = end - j;                      // 0..7, cv already holds tail indices
    for (int e = 0; e < tail; ++e) {
        int s = __shfl(cv, e, 8);
        float2 v = hsf[(size_t)s * 16 + lane];
        __half2* vh = (__half2*)&v;
        float2 w0 = __half22float2(vh[0]), w1 = __half22float2(vh[1]);
        a0 += w0.x; a1 += w0.y; a2 += w1.x; a3 += w1.y;
    }
    const float dv = dinv[node];
    float4 bb = ((const float4*)b1)[lane];
    __half2 p0 = __floats2half2_rn(fmaxf(dv * a0 + bb.x, 0.f), fmaxf(dv * a1 + bb.y, 0.f));
    __half2 p1 = __floats2half2_rn(fmaxf(dv * a2 + bb.z, 0.f), fmaxf(dv * a3 + bb.w, 0.f));
    sh2[nl][lane * 2] = p0;
    sh2[nl][lane * 2 + 1] = p1;
    __syncthreads();                               // covers sW and sh2

    // gemm2 phase: thread -> (node nl, out channels oc, oc+1); k order 0..63 sequential
    const int oc = lane * 2;
    float o0 = 0.f, o1 = 0.f;
#pragma unroll
    for (int k2 = 0; k2 < HID_C / 2; ++k2) {
        float2 hv = __half22float2(sh2[nl][k2]);
        const float* w0 = sW + (2 * k2) * OUT_C + oc;
        const float* w1 = sW + (2 * k2 + 1) * OUT_C + oc;
        o0 = fmaf(hv.x, w0[0], o0); o1 = fmaf(hv.x, w0[1], o1);
        o0 = fmaf(hv.y, w1[0], o0); o1 = fmaf(hv.y, w1[1], o1);
    }
    *(__half2*)(gs + (size_t)node * OUT_C + oc) = __floats2half2_rn(o0 * dv, o1 * dv);
}

// ---- layer-2 aggregate: 8 lanes x float2 per node (8 nodes/wave), full 64 B rows,
//      same coalesced-col + shfl + prefetch structure. ----
__global__ void agg2_kernel(const int* __restrict__ row_beg, const int* __restrict__ row_end,
                            const int* __restrict__ col,
                            const float2* __restrict__ gsf, const float* __restrict__ dinv,
                            const float* __restrict__ b2, float* __restrict__ out) {
    const int node = blockIdx.x * 32 + (threadIdx.x >> 3);
    const int lane = threadIdx.x & 7;              // float2 index: channels 4*lane..4*lane+3
    if (node >= N_NODES) return;
    const int beg = row_beg[node], end = row_end[node];
    float2 u = gsf[(size_t)node * 8 + lane];       // self loop
    __half2* uh = (__half2*)&u;
    float2 t0 = __half22float2(uh[0]), t1 = __half22float2(uh[1]);
    float a0 = t0.x, a1 = t0.y, a2 = t1.x, a3 = t1.y;

    int j = beg;
    int idx0 = j + lane;
    int cv = (idx0 < end) ? col[idx0] : 0;
    while (j + 8 <= end) {
        int jn = j + 8;
        int idxn = jn + lane;
        int cvn = (idxn < end) ? col[idxn] : 0;    // prefetch next chunk
        int s[8];
#pragma unroll
        for (int e = 0; e < 8; ++e) s[e] = __shfl(cv, e, 8);
        float2 v[8];
#pragma unroll
        for (int e = 0; e < 8; ++e) v[e] = gsf[(size_t)s[e] * 8 + lane];
        cv = cvn;
#pragma unroll
        for (int e = 0; e < 8; ++e) {
            __half2* vh = (__half2*)&v[e];
            float2 w0 = __half22float2(vh[0]), w1 = __half22float2(vh[1]);
            a0 += w0.x; a1 += w0.y; a2 += w1.x; a3 += w1.y;
        }
        j = jn;
    }
    const int tail = end - j;
    for (int e = 0; e < tail; ++e) {
        int s = __shfl(cv, e, 8);
        float2 v = gsf[(size_t)s * 8 + lane];
        __half2* vh = (__half2*)&v;
        float2 w0 = __half22float2(vh[0]), w1 = __half22float2(vh[1]);
        a0 += w0.x; a1 += w0.y; a2 += w1.x; a3 += w1.y;
    }
    float dv = dinv[node];
    float4 bb = ((const float4*)b2)[lane];
    float4 o;
    o.x = dv * a0 + bb.x;
    o.y = dv * a1 + bb.y;
    o.z = dv * a2 + bb.z;
    o.w = dv * a3 + bb.w;
    *(float4*)(out + (size_t)node * OUT_C + lane * 4) = o;
}

extern "C" void kernel_launch(void* const* d_in, const int* in_sizes, int n_in,
                              void* d_out, int out_size, void* d_ws, size_t ws_size,
                              hipStream_t stream) {
    const float* x  = (const float*)d_in[0];   // [N,128]
    const int*   ei = (const int*)d_in[1];     // [2,E]
    const float* W1 = (const float*)d_in[2];   // [128,64]
    const float* b1 = (const float*)d_in[3];   // [64]
    const float* W2 = (const float*)d_in[4];   // [64,32]
    const float* b2 = (const float*)d_in[5];   // [32]
    float* out = (float*)d_out;                // [N,32]

    const int* srcv = ei;
    const int* dstv = ei + E_EDGES;

    // workspace layout (~33 MB; ws is ~268 MB). gs is a DEDICATED region (agg1 reads
    // hs while writing gs -> must not alias).
    float* dinv  = (float*)d_ws;                            // N floats
    __half* hs   = (__half*)(dinv + N_NODES);               // N*64 halves
    __half* gs   = hs + (size_t)N_NODES * HID_C;            // N*32 halves
    int* row_beg = (int*)(gs + (size_t)N_NODES * OUT_C);    // N
    int* row_end = row_beg + N_NODES;                       // N
    int* gcur    = row_end + N_NODES;                       // NBUCK (pad to 1568)
    unsigned* pairs = (unsigned*)(gcur + 1568);             // NBUCK*MAXB (padded buckets)
    int* col = (int*)pairs;

    // CSR build: atomic bucket-window reservation
    zero_gcur_kernel<<<(NBUCK + 255) / 256, 256, 0, stream>>>(gcur);
    bucket_scatter_kernel<<<NCHUNK, 1024, 0, stream>>>(srcv, dstv, gcur, pairs);
    bucket_sort_kernel<<<NBUCK, 256, 0, stream>>>(gcur, pairs, row_beg, row_end, dinv);

    // layer 1 GEMM (64 rows/block, two-tile LDS staging, grid 1563)
    gemm1_kernel<<<(N_NODES + 63) / 64, 256, 0, stream>>>(x, W1, dinv, hs);

    // layer-1 aggregate + fused layer-2 GEMM
    agg1_kernel<<<N_NODES / 16, 256, 0, stream>>>(row_beg, row_end, col,
                                                  (const float2*)hs, dinv, b1, W2, gs);

    // layer-2 aggregate
    agg2_kernel<<<(N_NODES + 31) / 32, 256, 0, stream>>>(row_beg, row_end, col,
                                                         (const float2*)gs, dinv, b2, out);
}